// Round 2
// baseline (103.047 us; speedup 1.0000x reference)
//
#include <hip/hip_runtime.h>

// Problem constants (match reference)
#define BB    32
#define N_OPC 512
#define N_MAC 64
#define FF    8
#define HH    128
#define OO    8
#define TM    16      // rows per block
#define ASTR  132     // activation LDS row stride in floats ([TM][ASTR]), 16B-aligned rows

__device__ __forceinline__ float elu_f(float x) {
    return x > 0.0f ? x : (__expf(x) - 1.0f);
}

// Paired input layer for the two branch MLPs: K -> 128 with ELU.
// tid&127 = output column j, tid>>7 selects branch (wave-uniform).
// x row-major [TM][K] in LDS (read fully broadcast), out row-major [TM][ASTR].
template<int K>
__device__ __forceinline__ void layer_in_pair(const float* __restrict__ x0,
                                              const float* __restrict__ x1,
                                              const float* __restrict__ w0g, const float* __restrict__ b0g,
                                              const float* __restrict__ w1g, const float* __restrict__ b1g,
                                              float (* __restrict__ o0)[ASTR],
                                              float (* __restrict__ o1)[ASTR], int tid)
{
    const int j = tid & (HH - 1);
    const int m = tid >> 7;                 // wave-uniform branch select
    const float* x  = m ? x1  : x0;
    const float* w  = m ? w1g : w0g;
    const float* bv = m ? b1g : b0g;
    float (*o)[ASTR] = m ? o1 : o0;
    float wr[K];
    #pragma unroll
    for (int k = 0; k < K; ++k) wr[k] = w[k * HH + j];
    const float bj = bv[j];
    #pragma unroll
    for (int r = 0; r < TM; ++r) {
        float a = bj;
        #pragma unroll
        for (int k = 0; k < K; ++k) a = fmaf(x[r * K + k], wr[k], a);
        o[r][j] = elu_f(a);
    }
}

// Input layer for final projection (single MLP, K=16): tid&127 = col, tid>>7 = row half.
__device__ __forceinline__ void layer_in_proj(const float (* __restrict__ cat)[2 * OO],
                                              const float* __restrict__ w,
                                              const float* __restrict__ b,
                                              float (* __restrict__ o)[ASTR], int tid)
{
    const int j  = tid & (HH - 1);
    const int rh = tid >> 7;
    float wr[2 * OO];
    #pragma unroll
    for (int k = 0; k < 2 * OO; ++k) wr[k] = w[k * HH + j];
    const float bj = b[j];
    #pragma unroll
    for (int i = 0; i < TM / 2; ++i) {
        const int r = rh * (TM / 2) + i;
        float a = bj;
        #pragma unroll
        for (int k = 0; k < 2 * OO; ++k) a = fmaf(cat[r][k], wr[k], a);
        o[r][j] = elu_f(a);
    }
}

// Heavy layer: 128 -> 128 with ELU. 1 row x 8 cols per thread.
// Per 4 k: one ds_read_b128 of h (broadcast 4-way) + 8 global b128 weight loads
// (16-way lane-shared -> 128B/wave useful, L1/L2-hot) + 32 FMAs.
__device__ __forceinline__ void layer_hh_one(const float (* __restrict__ in)[ASTR],
                                             const float* __restrict__ w,
                                             const float* __restrict__ b,
                                             float (* __restrict__ outb)[ASTR], int tid)
{
    const int r  = tid & (TM - 1);          // row 0..15
    const int j0 = (tid >> 4) * 8;          // col base, 16 col-tiles of 8
    float acc[8];
    {
        const float4 b0 = *(const float4*)(b + j0);
        const float4 b1 = *(const float4*)(b + j0 + 4);
        acc[0] = b0.x; acc[1] = b0.y; acc[2] = b0.z; acc[3] = b0.w;
        acc[4] = b1.x; acc[5] = b1.y; acc[6] = b1.z; acc[7] = b1.w;
    }
    #pragma unroll 2
    for (int k = 0; k < HH; k += 4) {
        const float4 hv = *(const float4*)&in[r][k];
        #pragma unroll
        for (int kk = 0; kk < 4; ++kk) {
            const float hs = (kk == 0) ? hv.x : (kk == 1) ? hv.y : (kk == 2) ? hv.z : hv.w;
            const float4 w0 = *(const float4*)(w + (k + kk) * HH + j0);
            const float4 w1 = *(const float4*)(w + (k + kk) * HH + j0 + 4);
            acc[0] = fmaf(hs, w0.x, acc[0]);
            acc[1] = fmaf(hs, w0.y, acc[1]);
            acc[2] = fmaf(hs, w0.z, acc[2]);
            acc[3] = fmaf(hs, w0.w, acc[3]);
            acc[4] = fmaf(hs, w1.x, acc[4]);
            acc[5] = fmaf(hs, w1.y, acc[5]);
            acc[6] = fmaf(hs, w1.z, acc[6]);
            acc[7] = fmaf(hs, w1.w, acc[7]);
        }
    }
    #pragma unroll
    for (int c = 0; c < 8; ++c) outb[r][j0 + c] = elu_f(acc[c]);
}

// Paired output layer for the two branches: 128 -> 8, full K per thread,
// writes elu(result) directly into catS. tid>>7 = branch (wave-uniform).
__device__ __forceinline__ void layer_ho_pair(const float (* __restrict__ g0)[ASTR],
                                              const float (* __restrict__ g1)[ASTR],
                                              const float* __restrict__ w30, const float* __restrict__ b30,
                                              const float* __restrict__ w31, const float* __restrict__ b31,
                                              float (* __restrict__ cat)[2 * OO], int tid)
{
    const int item = tid & 127;
    const int m    = tid >> 7;
    const int r = item >> 3, o = item & 7;
    const float (*g)[ASTR]  = m ? g1 : g0;
    const float* w3 = m ? w31 : w30;
    const float* b3 = m ? b31 : b30;
    float a = b3[o];
    #pragma unroll 8
    for (int k = 0; k < HH; ++k) a = fmaf(g[r][k], w3[k * OO + o], a);
    cat[r][m * OO + o] = elu_f(a);
}

// Final output layer: 128 -> 8 with split-K across the two half-blocks.
__device__ __forceinline__ void layer_ho_final(const float (* __restrict__ g)[ASTR],
                                               const float* __restrict__ w3,
                                               float (* __restrict__ part)[TM][OO], int tid)
{
    const int item = tid & 127;
    const int half = tid >> 7;
    const int r = item >> 3, o = item & 7;
    const int k0 = half * (HH / 2);
    float a = 0.0f;
    #pragma unroll 8
    for (int kk = 0; kk < HH / 2; ++kk) {
        const int k = k0 + kk;
        a = fmaf(g[r][k], w3[k * OO + o], a);
    }
    part[half][r][o] = a;
}

__global__ __launch_bounds__(256, 4) void mlps_kernel(
    const int*   __restrict__ adj,   // (B, N_OP, N_MA) int32
    const float* __restrict__ fop,   // (B, N_OP, F)
    const float* __restrict__ fmab,  // (B, N_MA, F)
    const float* __restrict__ l0w1, const float* __restrict__ l0b1,
    const float* __restrict__ l0w2, const float* __restrict__ l0b2,
    const float* __restrict__ l0w3, const float* __restrict__ l0b3,
    const float* __restrict__ l1w1, const float* __restrict__ l1b1,
    const float* __restrict__ l1w2, const float* __restrict__ l1b2,
    const float* __restrict__ l1w3, const float* __restrict__ l1b3,
    const float* __restrict__ pw1,  const float* __restrict__ pb1,
    const float* __restrict__ pw2,  const float* __restrict__ pb2,
    const float* __restrict__ pw3,  const float* __restrict__ pb3,
    float* __restrict__ out)
{
    __shared__ float fmS[N_MAC * FF];     // machine feats for this batch (2 KB)
    __shared__ float xinS[TM][FF];        // aggregated machine feats
    __shared__ float xopS[TM][FF];        // op feats
    __shared__ float catS[TM][2 * OO];    // elu(concat(emb0, emb1))
    __shared__ float h0[TM][ASTR];        // activations, row-major
    __shared__ float h1[TM][ASTR];
    __shared__ float g0[TM][ASTR];
    __shared__ float g1[TM][ASTR];
    __shared__ float part[2][TM][OO];     // final split-K partials

    const int tid  = threadIdx.x;
    const int row0 = blockIdx.x * TM;     // global row base (b*N_OP + n)
    const int b    = row0 / N_OPC;        // TM | N_OP -> single batch per block

    // ---- stage machine feats + op feats
    {
        const float* msrc = fmab + b * N_MAC * FF;
        fmS[tid]       = msrc[tid];
        fmS[tid + 256] = msrc[tid + 256];
        if (tid < TM * FF)
            ((float*)xopS)[tid] = fop[row0 * FF + tid];
    }
    __syncthreads();

    // ---- aggregation: xin[r][f] = sum_m adj[r][m] * fm[m][f]
    if (tid < TM * FF) {
        const int r = tid >> 3, f = tid & 7;
        const int* arow = adj + (row0 + r) * N_MAC;
        float a = 0.0f;
        #pragma unroll
        for (int m4 = 0; m4 < N_MAC; m4 += 4) {
            const int4 av = *(const int4*)(arow + m4);
            a = fmaf((float)av.x, fmS[(m4 + 0) * FF + f], a);
            a = fmaf((float)av.y, fmS[(m4 + 1) * FF + f], a);
            a = fmaf((float)av.z, fmS[(m4 + 2) * FF + f], a);
            a = fmaf((float)av.w, fmS[(m4 + 3) * FF + f], a);
        }
        xinS[r][f] = a;
    }
    __syncthreads();

    // ---- both branch MLPs in paired phases
    layer_in_pair<FF>(&xinS[0][0], &xopS[0][0], l0w1, l0b1, l1w1, l1b1, h0, h1, tid);
    __syncthreads();
    layer_hh_one(h0, l0w2, l0b2, g0, tid);
    layer_hh_one(h1, l1w2, l1b2, g1, tid);
    __syncthreads();
    layer_ho_pair(g0, g1, l0w3, l0b3, l1w3, l1b3, catS, tid);
    __syncthreads();

    // ---- final projection: elu(cat) -> 128 -> 128 -> 8
    layer_in_proj(catS, pw1, pb1, h0, tid);
    __syncthreads();
    layer_hh_one(h0, pw2, pb2, g0, tid);
    __syncthreads();
    layer_ho_final(g0, pw3, part, tid);
    __syncthreads();
    if (tid < TM * OO) {
        const int r = tid >> 3, o = tid & 7;
        out[row0 * OO + tid] = part[0][r][o] + part[1][r][o] + pb3[o];
    }
}

extern "C" void kernel_launch(void* const* d_in, const int* in_sizes, int n_in,
                              void* d_out, int out_size, void* d_ws, size_t ws_size,
                              hipStream_t stream) {
    (void)in_sizes; (void)n_in; (void)out_size; (void)d_ws; (void)ws_size;
    const int*   adj  = (const int*)  d_in[0];
    const float* fop  = (const float*)d_in[1];
    const float* fmab = (const float*)d_in[2];
    const float* l0w1 = (const float*)d_in[3];
    const float* l0b1 = (const float*)d_in[4];
    const float* l0w2 = (const float*)d_in[5];
    const float* l0b2 = (const float*)d_in[6];
    const float* l0w3 = (const float*)d_in[7];
    const float* l0b3 = (const float*)d_in[8];
    const float* l1w1 = (const float*)d_in[9];
    const float* l1b1 = (const float*)d_in[10];
    const float* l1w2 = (const float*)d_in[11];
    const float* l1b2 = (const float*)d_in[12];
    const float* l1w3 = (const float*)d_in[13];
    const float* l1b3 = (const float*)d_in[14];
    const float* pw1  = (const float*)d_in[15];
    const float* pb1  = (const float*)d_in[16];
    const float* pw2  = (const float*)d_in[17];
    const float* pb2  = (const float*)d_in[18];
    const float* pw3  = (const float*)d_in[19];
    const float* pb3  = (const float*)d_in[20];
    float* out = (float*)d_out;

    const int nrows = BB * N_OPC;            // 16384
    const int grid  = nrows / TM;            // 1024 blocks
    mlps_kernel<<<dim3(grid), dim3(256), 0, stream>>>(
        adj, fop, fmab,
        l0w1, l0b1, l0w2, l0b2, l0w3, l0b3,
        l1w1, l1b1, l1w2, l1b2, l1w3, l1b3,
        pw1, pb1, pw2, pb2, pw3, pb3,
        out);
}

// Round 3
// 26.547 us; speedup vs baseline: 3.8816x; 3.8816x over previous
//
#include <hip/hip_runtime.h>

// Problem constants
#define BB    32
#define N_OPC 512
#define N_MAC 64
#define FF    8
#define HH    128
#define OO    8
#define TM    16
#define ASTRB 136   // activation LDS row stride in ushorts (272 B, 16B-aligned)

typedef __bf16 bf16x8 __attribute__((ext_vector_type(8)));
typedef float  f32x4  __attribute__((ext_vector_type(4)));

// ws layout (ushort units):
//   W2 hi: layer L (0=l0w2,1=l1w2,2=pw2) at L*16384          (3*16384)
//   W2 lo: 49152 + L*16384
//   W3 hi: 98304 + L*2048  (L: 0=l0w3,1=l1w3,2=pw3, padded to 16 cols)
//   W3 lo: 104448 + L*2048
#define WS_W2LO 49152
#define WS_W3HI 98304
#define WS_W3LO 104448

__device__ __forceinline__ ushort f2bf(float x) {
    union { float f; unsigned u; } c; c.f = x;
    unsigned r = c.u + 0x7fffu + ((c.u >> 16) & 1u);
    return (ushort)(r >> 16);
}
__device__ __forceinline__ float bf2f(ushort h) {
    union { unsigned u; float f; } c; c.u = ((unsigned)h) << 16; return c.f;
}
__device__ __forceinline__ float elu_f(float x) {
    return x > 0.0f ? x : (__expf(x) - 1.0f);
}
__device__ __forceinline__ void split_store(float v, ushort* hi, ushort* lo, int off) {
    ushort h = f2bf(v);
    hi[off] = h;
    lo[off] = f2bf(v - bf2f(h));
}

// ---- weight prep: fp32 -> bf16 hi/lo in MFMA B-fragment order ----
// B-frag for 16x16x32: lane = (k_octet<<4)|col, elem i = k&7; frag idx = (nt*4+ks).
__global__ void prep_kernel(const float* __restrict__ w20, const float* __restrict__ w21,
                            const float* __restrict__ w22,
                            const float* __restrict__ w30, const float* __restrict__ w31,
                            const float* __restrict__ w32,
                            ushort* __restrict__ ws)
{
    const int gid = blockIdx.x * 256 + threadIdx.x;
    if (gid < 3 * 16384) {
        const int layer = gid >> 14, idx = gid & 16383;
        const float* w = layer == 0 ? w20 : layer == 1 ? w21 : w22;
        const int k = idx >> 7, j = idx & 127;
        const float x = w[idx];
        const int ks = k >> 5, kk = k & 31, nt = j >> 4, jj = j & 15;
        const int lane = ((kk >> 3) << 4) | jj, i = kk & 7;
        const int off = (((nt * 4 + ks) * 64 + lane) << 3) + i;
        const ushort hi = f2bf(x);
        const ushort lo = f2bf(x - bf2f(hi));
        ws[layer * 16384 + off]           = hi;
        ws[WS_W2LO + layer * 16384 + off] = lo;
    } else {
        const int g2 = gid - 3 * 16384;          // 0..6143
        const int layer = g2 >> 11, idx = g2 & 2047;
        const float* w = layer == 0 ? w30 : layer == 1 ? w31 : w32;
        const int i = idx & 7, lane = (idx >> 3) & 63, ks = idx >> 9;
        const int k = ks * 32 + (lane >> 4) * 8 + i, j = lane & 15;
        const float x = (j < OO) ? w[k * OO + j] : 0.0f;
        const ushort hi = f2bf(x);
        const ushort lo = f2bf(x - bf2f(hi));
        ws[WS_W3HI + layer * 2048 + idx] = hi;   // idx == (ks*64+lane)*8+i
        ws[WS_W3LO + layer * 2048 + idx] = lo;
    }
}

// ---- split-precision MFMA layer: NT col-tiles of 16, K=128 (4 ks) ----
// acc must be zero-initialized by caller. nt0 = global col-tile base for this wave.
template<int NT>
__device__ __forceinline__ void mfma_layer(const ushort* __restrict__ aHi,
                                           const ushort* __restrict__ aLo,
                                           const ushort* __restrict__ wHi,
                                           const ushort* __restrict__ wLo,
                                           int nt0, int lane, f32x4* acc)
{
    const int lrow = lane & 15, lk = lane >> 4;
    const bf16x8* BH = (const bf16x8*)wHi;
    const bf16x8* BL = (const bf16x8*)wLo;
    const int abase = lrow * ASTRB + lk * 8;
    const int fbase = nt0 * 4;
    bf16x8 bh = BH[fbase * 64 + lane];
    bf16x8 bl = BL[fbase * 64 + lane];
    #pragma unroll
    for (int t = 0; t < NT * 4; ++t) {
        const int nt = t >> 2, ks = t & 3;
        const bf16x8 bhc = bh, blc = bl;
        if (t + 1 < NT * 4) {
            bh = BH[(fbase + t + 1) * 64 + lane];
            bl = BL[(fbase + t + 1) * 64 + lane];
        }
        const bf16x8 ah = *(const bf16x8*)(aHi + abase + ks * 32);
        const bf16x8 al = *(const bf16x8*)(aLo + abase + ks * 32);
        acc[nt] = __builtin_amdgcn_mfma_f32_16x16x32_bf16(ah, bhc, acc[nt], 0, 0, 0);
        acc[nt] = __builtin_amdgcn_mfma_f32_16x16x32_bf16(ah, blc, acc[nt], 0, 0, 0);
        acc[nt] = __builtin_amdgcn_mfma_f32_16x16x32_bf16(al, bhc, acc[nt], 0, 0, 0);
    }
}

__global__ __launch_bounds__(256, 4) void mlps_kernel(
    const int*   __restrict__ adj,
    const float* __restrict__ fop,
    const float* __restrict__ fmab,
    const float* __restrict__ l0w1, const float* __restrict__ l0b1,
    const float* __restrict__ l0b2, const float* __restrict__ l0b3,
    const float* __restrict__ l1w1, const float* __restrict__ l1b1,
    const float* __restrict__ l1b2, const float* __restrict__ l1b3,
    const float* __restrict__ pw1,  const float* __restrict__ pb1,
    const float* __restrict__ pb2,  const float* __restrict__ pb3,
    const ushort* __restrict__ wsf,
    float* __restrict__ out)
{
    __shared__ __align__(16) ushort hbuf[4][TM * ASTRB]; // h0hi,h0lo,h1hi,h1lo
    __shared__ __align__(16) ushort gbuf[4][TM * ASTRB]; // g0hi,g0lo,g1hi,g1lo
    __shared__ float fmS[N_MAC * FF];
    __shared__ float xinS[TM * FF];
    __shared__ float xopS[TM * FF];
    __shared__ float catS[TM * 16];

    const int tid  = threadIdx.x;
    const int row0 = blockIdx.x * TM;
    const int b    = row0 / N_OPC;

    // ---- stage machine feats + op feats
    {
        const float* msrc = fmab + b * N_MAC * FF;
        fmS[tid]       = msrc[tid];
        fmS[tid + 256] = msrc[tid + 256];
        if (tid < TM * FF) xopS[tid] = fop[row0 * FF + tid];
    }
    __syncthreads();

    // ---- aggregation: xin[r][f] = sum_m adj[r][m] * fm[m][f]
    if (tid < TM * FF) {
        const int r = tid >> 3, f = tid & 7;
        const int* arow = adj + (row0 + r) * N_MAC;
        float a = 0.0f;
        #pragma unroll
        for (int m4 = 0; m4 < N_MAC; m4 += 4) {
            const int4 av = *(const int4*)(arow + m4);
            a = fmaf((float)av.x, fmS[(m4 + 0) * FF + f], a);
            a = fmaf((float)av.y, fmS[(m4 + 1) * FF + f], a);
            a = fmaf((float)av.z, fmS[(m4 + 2) * FF + f], a);
            a = fmaf((float)av.w, fmS[(m4 + 3) * FF + f], a);
        }
        xinS[tid] = a;
    }
    __syncthreads();

    // ---- paired input layers (K=8 -> 128, VALU), write split bf16
    {
        const int j = tid & 127, m = tid >> 7;
        const float* x  = m ? xopS : xinS;
        const float* w  = m ? l1w1 : l0w1;
        const float* bv = m ? l1b1 : l0b1;
        ushort* dhi = m ? hbuf[2] : hbuf[0];
        ushort* dlo = m ? hbuf[3] : hbuf[1];
        float wr[FF];
        #pragma unroll
        for (int k = 0; k < FF; ++k) wr[k] = w[k * HH + j];
        const float bj = bv[j];
        #pragma unroll
        for (int r = 0; r < TM; ++r) {
            float a = bj;
            #pragma unroll
            for (int k = 0; k < FF; ++k) a = fmaf(x[r * FF + k], wr[k], a);
            split_store(elu_f(a), dhi, dlo, r * ASTRB + j);
        }
    }
    __syncthreads();

    // ---- paired heavy layers (128x128, MFMA split): waves 0,1 -> br0; 2,3 -> br1
    {
        const int w = tid >> 6, lane = tid & 63;
        const int br = w >> 1, nh = w & 1;
        const ushort* wHi = wsf + br * 16384;
        const ushort* wLo = wsf + WS_W2LO + br * 16384;
        const float*  b2  = br ? l1b2 : l0b2;
        ushort* dhi = gbuf[br * 2], * dlo = gbuf[br * 2 + 1];
        f32x4 acc[4] = {{0,0,0,0},{0,0,0,0},{0,0,0,0},{0,0,0,0}};
        mfma_layer<4>(hbuf[br * 2], hbuf[br * 2 + 1], wHi, wLo, nh * 4, lane, acc);
        const int col = lane & 15, rbase = (lane >> 4) * 4;
        #pragma unroll
        for (int nt = 0; nt < 4; ++nt) {
            const int j = (nh * 4 + nt) * 16 + col;
            const float bb = b2[j];
            #pragma unroll
            for (int i = 0; i < 4; ++i)
                split_store(elu_f(acc[nt][i] + bb), dhi, dlo, (rbase + i) * ASTRB + j);
        }
    }
    __syncthreads();

    // ---- paired output layers (128 -> 8, MFMA, padded to 16): waves 0 and 2
    {
        const int w = tid >> 6, lane = tid & 63;
        if ((w & 1) == 0) {
            const int br = w >> 1;
            const ushort* wHi = wsf + WS_W3HI + br * 2048;
            const ushort* wLo = wsf + WS_W3LO + br * 2048;
            const float*  b3  = br ? l1b3 : l0b3;
            f32x4 acc[1] = {{0,0,0,0}};
            mfma_layer<1>(gbuf[br * 2], gbuf[br * 2 + 1], wHi, wLo, 0, lane, acc);
            const int col = lane & 15, rbase = (lane >> 4) * 4;
            if (col < OO) {
                #pragma unroll
                for (int i = 0; i < 4; ++i)
                    catS[(rbase + i) * 16 + br * OO + col] = elu_f(acc[0][i] + b3[col]);
            }
        }
    }
    __syncthreads();

    // ---- proj input layer (K=16 -> 128, VALU)
    {
        const int j = tid & 127, rh = tid >> 7;
        float wr[16];
        #pragma unroll
        for (int k = 0; k < 16; ++k) wr[k] = pw1[k * HH + j];
        const float bj = pb1[j];
        #pragma unroll
        for (int ri = 0; ri < 8; ++ri) {
            const int r = rh * 8 + ri;
            float a = bj;
            #pragma unroll
            for (int k = 0; k < 16; ++k) a = fmaf(catS[r * 16 + k], wr[k], a);
            split_store(elu_f(a), hbuf[0], hbuf[1], r * ASTRB + j);
        }
    }
    __syncthreads();

    // ---- proj heavy layer (128x128, MFMA): 4 waves x 2 col-tiles
    {
        const int w = tid >> 6, lane = tid & 63;
        const ushort* wHi = wsf + 2 * 16384;
        const ushort* wLo = wsf + WS_W2LO + 2 * 16384;
        f32x4 acc[2] = {{0,0,0,0},{0,0,0,0}};
        mfma_layer<2>(hbuf[0], hbuf[1], wHi, wLo, w * 2, lane, acc);
        const int col = lane & 15, rbase = (lane >> 4) * 4;
        #pragma unroll
        for (int nt = 0; nt < 2; ++nt) {
            const int j = (w * 2 + nt) * 16 + col;
            const float bb = pb2[j];
            #pragma unroll
            for (int i = 0; i < 4; ++i)
                split_store(elu_f(acc[nt][i] + bb), gbuf[0], gbuf[1], (rbase + i) * ASTRB + j);
        }
    }
    __syncthreads();

    // ---- proj output layer (128 -> 8, MFMA on wave 0), direct global store
    if (tid < 64) {
        const int lane = tid;
        const ushort* wHi = wsf + WS_W3HI + 2 * 2048;
        const ushort* wLo = wsf + WS_W3LO + 2 * 2048;
        f32x4 acc[1] = {{0,0,0,0}};
        mfma_layer<1>(gbuf[0], gbuf[1], wHi, wLo, 0, lane, acc);
        const int col = lane & 15, rbase = (lane >> 4) * 4;
        if (col < OO) {
            #pragma unroll
            for (int i = 0; i < 4; ++i)
                out[(row0 + rbase + i) * OO + col] = acc[0][i] + pb3[col];
        }
    }
}

extern "C" void kernel_launch(void* const* d_in, const int* in_sizes, int n_in,
                              void* d_out, int out_size, void* d_ws, size_t ws_size,
                              hipStream_t stream) {
    (void)in_sizes; (void)n_in; (void)out_size; (void)ws_size;
    const int*   adj  = (const int*)  d_in[0];
    const float* fop  = (const float*)d_in[1];
    const float* fmab = (const float*)d_in[2];
    const float* l0w1 = (const float*)d_in[3];
    const float* l0b1 = (const float*)d_in[4];
    const float* l0w2 = (const float*)d_in[5];
    const float* l0b2 = (const float*)d_in[6];
    const float* l0w3 = (const float*)d_in[7];
    const float* l0b3 = (const float*)d_in[8];
    const float* l1w1 = (const float*)d_in[9];
    const float* l1b1 = (const float*)d_in[10];
    const float* l1w2 = (const float*)d_in[11];
    const float* l1b2 = (const float*)d_in[12];
    const float* l1w3 = (const float*)d_in[13];
    const float* l1b3 = (const float*)d_in[14];
    const float* pw1  = (const float*)d_in[15];
    const float* pb1  = (const float*)d_in[16];
    const float* pw2  = (const float*)d_in[17];
    const float* pb2  = (const float*)d_in[18];
    const float* pw3  = (const float*)d_in[19];
    const float* pb3  = (const float*)d_in[20];
    float* out = (float*)d_out;
    ushort* wsf = (ushort*)d_ws;

    prep_kernel<<<dim3(216), dim3(256), 0, stream>>>(l0w2, l1w2, pw2, l0w3, l1w3, pw3, wsf);

    const int grid = (BB * N_OPC) / TM;   // 1024
    mlps_kernel<<<dim3(grid), dim3(256), 0, stream>>>(
        adj, fop, fmab,
        l0w1, l0b1, l0b2, l0b3,
        l1w1, l1b1, l1b2, l1b3,
        pw1, pb1, pb2, pb3,
        wsf, out);
}

// Round 4
// 23.113 us; speedup vs baseline: 4.4584x; 1.1486x over previous
//
#include <hip/hip_runtime.h>

// Problem constants
#define BB    32
#define N_OPC 512
#define N_MAC 64
#define FF    8
#define HH    128
#define OO    8
#define TM    32      // rows per block
#define ASTRB 136     // activation plane row stride (ushorts); 272B = 17*16 -> conflict-free b128

typedef __bf16 bf16x8 __attribute__((ext_vector_type(8)));
typedef float  f32x4  __attribute__((ext_vector_type(4)));

// ws layout (ushort offsets). B-frag element: frag[(jt*KS+ks)*64+lane][i] =
//   W[k = ks*32 + (lane>>4)*8 + i][j = jt*16 + (lane&15)], zero-padded.
#define WS_W2HI 0        // L*16384, L: 0=l0w2 1=l1w2 2=pw2   (8 jt x 4 ks)
#define WS_W2LO 49152
#define WS_W3HI 98304    // L*2048,  L: 0=l0w3 1=l1w3 2=pw3   (1 jt x 4 ks, cols padded to 16)
#define WS_W3LO 104448
#define WS_W1HI 110592   // L*4096,  L: 0=l0w1 1=l1w1 2=pw1   (8 jt x 1 ks, K padded to 32)
#define WS_W1LO 122880

__device__ __forceinline__ ushort f2bf(float x) {
    union { float f; unsigned u; } c; c.f = x;
    unsigned r = c.u + 0x7fffu + ((c.u >> 16) & 1u);
    return (ushort)(r >> 16);
}
__device__ __forceinline__ float bf2f(ushort h) {
    union { unsigned u; float f; } c; c.u = ((unsigned)h) << 16; return c.f;
}
__device__ __forceinline__ float elu_f(float x) {
    return x > 0.0f ? x : (__expf(x) - 1.0f);
}
__device__ __forceinline__ void split_store(float v, ushort* hi, ushort* lo, int off) {
    ushort h = f2bf(v);
    hi[off] = h;
    lo[off] = f2bf(v - bf2f(h));
}

// ---- weight prep: fp32 -> bf16 hi/lo B-fragments ----
__global__ void prep_kernel(const float* __restrict__ w20, const float* __restrict__ w21,
                            const float* __restrict__ w22,
                            const float* __restrict__ w30, const float* __restrict__ w31,
                            const float* __restrict__ w32,
                            const float* __restrict__ w10, const float* __restrict__ w11,
                            const float* __restrict__ w12,
                            ushort* __restrict__ ws)
{
    const int gid = blockIdx.x * 256 + threadIdx.x;
    if (gid < 3 * 16384) {                       // W2: 128x128
        const int layer = gid >> 14, idx = gid & 16383;
        const float* w = layer == 0 ? w20 : layer == 1 ? w21 : w22;
        const int k = idx >> 7, j = idx & 127;
        const float x = w[idx];
        const int ks = k >> 5, kk = k & 31, jt = j >> 4, jj = j & 15;
        const int lane = ((kk >> 3) << 4) | jj, i = kk & 7;
        const int off = (((jt * 4 + ks) * 64 + lane) << 3) + i;
        const ushort hi = f2bf(x);
        ws[WS_W2HI + layer * 16384 + off] = hi;
        ws[WS_W2LO + layer * 16384 + off] = f2bf(x - bf2f(hi));
    } else if (gid < 3 * 16384 + 3 * 2048) {     // W3: 128x8 padded to 16 cols
        const int g2 = gid - 3 * 16384;
        const int layer = g2 >> 11, idx = g2 & 2047;
        const float* w = layer == 0 ? w30 : layer == 1 ? w31 : w32;
        const int i = idx & 7, lane = (idx >> 3) & 63, ks = idx >> 9;
        const int k = ks * 32 + (lane >> 4) * 8 + i, j = lane & 15;
        const float x = (j < OO) ? w[k * OO + j] : 0.0f;
        const ushort hi = f2bf(x);
        ws[WS_W3HI + layer * 2048 + idx] = hi;
        ws[WS_W3LO + layer * 2048 + idx] = f2bf(x - bf2f(hi));
    } else {                                     // W1: Kx128, K padded to 32
        const int g1 = gid - (3 * 16384 + 3 * 2048);
        const int layer = g1 >> 12, idx = g1 & 4095;
        const float* w = layer == 0 ? w10 : layer == 1 ? w11 : w12;
        const int i = idx & 7, lane = (idx >> 3) & 63, jt = idx >> 9;
        const int k = (lane >> 4) * 8 + i, j = jt * 16 + (lane & 15);
        const int Kr = (layer == 2) ? 16 : 8;
        const float x = (k < Kr) ? w[k * HH + j] : 0.0f;
        const ushort hi = f2bf(x);
        ws[WS_W1HI + layer * 4096 + idx] = hi;
        ws[WS_W1LO + layer * 4096 + idx] = f2bf(x - bf2f(hi));
    }
}

// ---- full-K (128) split-precision MFMA: acc[jtl][rt] += X[rt] * W[jt0+jtl] ----
template<int NJT, int NRT>
__device__ __forceinline__ void mfma_fullK(const ushort* __restrict__ aH,
                                           const ushort* __restrict__ aL,
                                           const ushort* __restrict__ wH,
                                           const ushort* __restrict__ wL,
                                           int jt0, int rowbase, int lane,
                                           f32x4 (* __restrict__ acc)[NRT])
{
    const int lrow = lane & 15, lk = lane >> 4;
    const bf16x8* BH = (const bf16x8*)wH;
    const bf16x8* BL = (const bf16x8*)wL;
    #pragma unroll
    for (int jtl = 0; jtl < NJT; ++jtl) {
        #pragma unroll
        for (int ks = 0; ks < 4; ++ks) {
            const bf16x8 bh = BH[((jt0 + jtl) * 4 + ks) * 64 + lane];
            const bf16x8 bl = BL[((jt0 + jtl) * 4 + ks) * 64 + lane];
            #pragma unroll
            for (int rt = 0; rt < NRT; ++rt) {
                const int ab = (rowbase + rt * 16 + lrow) * ASTRB + ks * 32 + lk * 8;
                const bf16x8 ah = *(const bf16x8*)(aH + ab);
                const bf16x8 al = *(const bf16x8*)(aL + ab);
                acc[jtl][rt] = __builtin_amdgcn_mfma_f32_16x16x32_bf16(ah, bh, acc[jtl][rt], 0, 0, 0);
                acc[jtl][rt] = __builtin_amdgcn_mfma_f32_16x16x32_bf16(ah, bl, acc[jtl][rt], 0, 0, 0);
                acc[jtl][rt] = __builtin_amdgcn_mfma_f32_16x16x32_bf16(al, bh, acc[jtl][rt], 0, 0, 0);
            }
        }
    }
}

__global__ __launch_bounds__(512, 4) void mlps_kernel(
    const int*   __restrict__ adj,
    const float* __restrict__ fop,
    const float* __restrict__ fmab,
    const float* __restrict__ l0b1, const float* __restrict__ l0b2, const float* __restrict__ l0b3,
    const float* __restrict__ l1b1, const float* __restrict__ l1b2, const float* __restrict__ l1b3,
    const float* __restrict__ pb1,  const float* __restrict__ pb2,  const float* __restrict__ pb3,
    const ushort* __restrict__ wsf,
    float* __restrict__ out)
{
    __shared__ __align__(16) ushort hbuf[2][2][TM * ASTRB];   // [br][hi/lo]
    __shared__ __align__(16) ushort gbuf[2][2][TM * ASTRB];
    __shared__ float fmS[N_MAC * FF];                         // 512
    __shared__ __align__(16) ushort xinH[TM * FF], xinL[TM * FF];
    __shared__ __align__(16) ushort xopH[TM * FF], xopL[TM * FF];
    __shared__ __align__(16) ushort catH[TM * 16], catL[TM * 16];

    const int tid  = threadIdx.x;
    const int wv   = tid >> 6;
    const int lane = tid & 63;
    const int lrow = lane & 15, lk = lane >> 4;
    const int col  = lrow;            // C-layout col
    const int row0 = blockIdx.x * TM;
    const int b    = row0 / N_OPC;

    // ---- stage: machine feats (fp32), op feats (split planes)
    fmS[tid] = fmab[b * N_MAC * FF + tid];
    if (tid < TM * FF)
        split_store(fop[row0 * FF + tid], xopH, xopL, tid);
    __syncthreads();

    // ---- aggregation: xin[r][f] = sum_m adj[r][m] * fm[m][f]  (split planes)
    if (tid < TM * FF) {
        const int r = tid >> 3, f = tid & 7;
        const int* arow = adj + (row0 + r) * N_MAC;
        float a = 0.0f;
        #pragma unroll
        for (int m4 = 0; m4 < N_MAC; m4 += 4) {
            const int4 av = *(const int4*)(arow + m4);
            a = fmaf((float)av.x, fmS[(m4 + 0) * FF + f], a);
            a = fmaf((float)av.y, fmS[(m4 + 1) * FF + f], a);
            a = fmaf((float)av.z, fmS[(m4 + 2) * FF + f], a);
            a = fmaf((float)av.w, fmS[(m4 + 3) * FF + f], a);
        }
        split_store(a, xinH, xinL, tid);
    }
    __syncthreads();

    // ---- input layers (K=8 pad 32, MFMA): waves 0-3 br0, 4-7 br1; 2 jtiles each
    {
        const int br = wv >> 2, jt0 = (wv & 3) * 2;
        const ushort* xH = br ? xopH : xinH;
        const ushort* xL = br ? xopL : xinL;
        const bf16x8* BH = (const bf16x8*)(wsf + WS_W1HI + br * 4096);
        const bf16x8* BL = (const bf16x8*)(wsf + WS_W1LO + br * 4096);
        const float* b1 = br ? l1b1 : l0b1;
        bf16x8 AH[2] = {}, AL[2] = {};
        if (lk == 0) {
            #pragma unroll
            for (int rt = 0; rt < 2; ++rt) {
                AH[rt] = *(const bf16x8*)(xH + (rt * 16 + lrow) * 8);
                AL[rt] = *(const bf16x8*)(xL + (rt * 16 + lrow) * 8);
            }
        }
        f32x4 acc[2][2] = {};
        #pragma unroll
        for (int jtl = 0; jtl < 2; ++jtl) {
            const bf16x8 bh = BH[(jt0 + jtl) * 64 + lane];
            const bf16x8 bl = BL[(jt0 + jtl) * 64 + lane];
            #pragma unroll
            for (int rt = 0; rt < 2; ++rt) {
                acc[jtl][rt] = __builtin_amdgcn_mfma_f32_16x16x32_bf16(AH[rt], bh, acc[jtl][rt], 0, 0, 0);
                acc[jtl][rt] = __builtin_amdgcn_mfma_f32_16x16x32_bf16(AH[rt], bl, acc[jtl][rt], 0, 0, 0);
                acc[jtl][rt] = __builtin_amdgcn_mfma_f32_16x16x32_bf16(AL[rt], bh, acc[jtl][rt], 0, 0, 0);
            }
        }
        ushort* dH = hbuf[br][0];
        ushort* dL = hbuf[br][1];
        #pragma unroll
        for (int jtl = 0; jtl < 2; ++jtl) {
            const int j = (jt0 + jtl) * 16 + col;
            const float bb = b1[j];
            #pragma unroll
            for (int rt = 0; rt < 2; ++rt)
                #pragma unroll
                for (int i = 0; i < 4; ++i)
                    split_store(elu_f(acc[jtl][rt][i] + bb), dH, dL,
                                (rt * 16 + lk * 4 + i) * ASTRB + j);
        }
    }
    __syncthreads();

    // ---- heavy layers (128x128, MFMA): waves 0-3 br0, 4-7 br1; 2 jtiles x 2 rowtiles
    {
        const int br = wv >> 2, jt0 = (wv & 3) * 2;
        f32x4 acc[2][2] = {};
        mfma_fullK<2, 2>(hbuf[br][0], hbuf[br][1],
                         wsf + WS_W2HI + br * 16384, wsf + WS_W2LO + br * 16384,
                         jt0, 0, lane, acc);
        const float* b2 = br ? l1b2 : l0b2;
        ushort* dH = gbuf[br][0];
        ushort* dL = gbuf[br][1];
        #pragma unroll
        for (int jtl = 0; jtl < 2; ++jtl) {
            const int j = (jt0 + jtl) * 16 + col;
            const float bb = b2[j];
            #pragma unroll
            for (int rt = 0; rt < 2; ++rt)
                #pragma unroll
                for (int i = 0; i < 4; ++i)
                    split_store(elu_f(acc[jtl][rt][i] + bb), dH, dL,
                                (rt * 16 + lk * 4 + i) * ASTRB + j);
        }
    }
    __syncthreads();

    // ---- branch output layers (128 -> 8 pad 16, MFMA): waves 0-3 only
    if (wv < 4) {
        const int br = wv >> 1, rt = wv & 1;
        f32x4 acc[1][1] = {};
        mfma_fullK<1, 1>(gbuf[br][0], gbuf[br][1],
                         wsf + WS_W3HI + br * 2048, wsf + WS_W3LO + br * 2048,
                         0, rt * 16, lane, acc);
        const float* b3 = br ? l1b3 : l0b3;
        if (col < OO) {
            #pragma unroll
            for (int i = 0; i < 4; ++i)
                split_store(elu_f(acc[0][0][i] + b3[col]), catH, catL,
                            (rt * 16 + lk * 4 + i) * 16 + br * OO + col);
        }
    }
    __syncthreads();

    // ---- proj input layer (K=16 pad 32, MFMA): wave wv -> jtile wv
    {
        const bf16x8* BH = (const bf16x8*)(wsf + WS_W1HI + 2 * 4096);
        const bf16x8* BL = (const bf16x8*)(wsf + WS_W1LO + 2 * 4096);
        bf16x8 AH[2] = {}, AL[2] = {};
        if (lk < 2) {
            #pragma unroll
            for (int rt = 0; rt < 2; ++rt) {
                AH[rt] = *(const bf16x8*)(catH + (rt * 16 + lrow) * 16 + lk * 8);
                AL[rt] = *(const bf16x8*)(catL + (rt * 16 + lrow) * 16 + lk * 8);
            }
        }
        f32x4 acc[2] = {};
        const bf16x8 bh = BH[wv * 64 + lane];
        const bf16x8 bl = BL[wv * 64 + lane];
        #pragma unroll
        for (int rt = 0; rt < 2; ++rt) {
            acc[rt] = __builtin_amdgcn_mfma_f32_16x16x32_bf16(AH[rt], bh, acc[rt], 0, 0, 0);
            acc[rt] = __builtin_amdgcn_mfma_f32_16x16x32_bf16(AH[rt], bl, acc[rt], 0, 0, 0);
            acc[rt] = __builtin_amdgcn_mfma_f32_16x16x32_bf16(AL[rt], bh, acc[rt], 0, 0, 0);
        }
        const int j = wv * 16 + col;
        const float bb = pb1[j];
        #pragma unroll
        for (int rt = 0; rt < 2; ++rt)
            #pragma unroll
            for (int i = 0; i < 4; ++i)
                split_store(elu_f(acc[rt][i] + bb), hbuf[0][0], hbuf[0][1],
                            (rt * 16 + lk * 4 + i) * ASTRB + j);
    }
    __syncthreads();

    // ---- proj heavy layer (128x128, MFMA): wave wv -> jtile wv, 2 rowtiles
    {
        f32x4 acc[1][2] = {};
        mfma_fullK<1, 2>(hbuf[0][0], hbuf[0][1],
                         wsf + WS_W2HI + 2 * 16384, wsf + WS_W2LO + 2 * 16384,
                         wv, 0, lane, acc);
        const int j = wv * 16 + col;
        const float bb = pb2[j];
        #pragma unroll
        for (int rt = 0; rt < 2; ++rt)
            #pragma unroll
            for (int i = 0; i < 4; ++i)
                split_store(elu_f(acc[0][rt][i] + bb), gbuf[0][0], gbuf[0][1],
                            (rt * 16 + lk * 4 + i) * ASTRB + j);
    }
    __syncthreads();

    // ---- proj output layer (128 -> 8, MFMA): waves 0,1 -> rowtiles, direct store
    if (wv < 2) {
        const int rt = wv;
        f32x4 acc[1][1] = {};
        mfma_fullK<1, 1>(gbuf[0][0], gbuf[0][1],
                         wsf + WS_W3HI + 2 * 2048, wsf + WS_W3LO + 2 * 2048,
                         0, rt * 16, lane, acc);
        if (col < OO) {
            #pragma unroll
            for (int i = 0; i < 4; ++i)
                out[(row0 + rt * 16 + lk * 4 + i) * OO + col] = acc[0][0][i] + pb3[col];
        }
    }
}

extern "C" void kernel_launch(void* const* d_in, const int* in_sizes, int n_in,
                              void* d_out, int out_size, void* d_ws, size_t ws_size,
                              hipStream_t stream) {
    (void)in_sizes; (void)n_in; (void)out_size; (void)ws_size;
    const int*   adj  = (const int*)  d_in[0];
    const float* fop  = (const float*)d_in[1];
    const float* fmab = (const float*)d_in[2];
    const float* l0w1 = (const float*)d_in[3];
    const float* l0b1 = (const float*)d_in[4];
    const float* l0w2 = (const float*)d_in[5];
    const float* l0b2 = (const float*)d_in[6];
    const float* l0w3 = (const float*)d_in[7];
    const float* l0b3 = (const float*)d_in[8];
    const float* l1w1 = (const float*)d_in[9];
    const float* l1b1 = (const float*)d_in[10];
    const float* l1w2 = (const float*)d_in[11];
    const float* l1b2 = (const float*)d_in[12];
    const float* l1w3 = (const float*)d_in[13];
    const float* l1b3 = (const float*)d_in[14];
    const float* pw1  = (const float*)d_in[15];
    const float* pb1  = (const float*)d_in[16];
    const float* pw2  = (const float*)d_in[17];
    const float* pb2  = (const float*)d_in[18];
    const float* pw3  = (const float*)d_in[19];
    const float* pb3  = (const float*)d_in[20];
    float* out = (float*)d_out;
    ushort* wsf = (ushort*)d_ws;

    // 49152 (W2) + 6144 (W3) + 12288 (W1) = 67584 items -> 264 blocks
    prep_kernel<<<dim3(264), dim3(256), 0, stream>>>(
        l0w2, l1w2, pw2, l0w3, l1w3, pw3, l0w1, l1w1, pw1, wsf);

    const int grid = (BB * N_OPC) / TM;   // 512
    mlps_kernel<<<dim3(grid), dim3(512), 0, stream>>>(
        adj, fop, fmab,
        l0b1, l0b2, l0b3,
        l1b1, l1b2, l1b3,
        pb1, pb2, pb3,
        wsf, out);
}

// Round 5
// 23.027 us; speedup vs baseline: 4.4750x; 1.0037x over previous
//
#include <hip/hip_runtime.h>

// Problem constants
#define BB    32
#define N_OPC 512
#define N_MAC 64
#define FF    8
#define HH    128
#define OO    8
#define TM    32      // rows per block
#define ASTRB 136     // activation plane row stride (ushorts)

typedef __bf16 bf16x8 __attribute__((ext_vector_type(8)));
typedef __bf16 bf16x4 __attribute__((ext_vector_type(4)));
typedef float  f32x4  __attribute__((ext_vector_type(4)));

// ws layout (ushort offsets). Frag element: frag[(jt*KS+ks)*64+lane][i] =
//   W[k = ks*32 + (lane>>4)*8 + i][j = jt*16 + (lane&15)], zero-padded.
// Used as the MFMA *A* operand (weights-as-A, swapped form).
#define WS_W2HI 0        // L*16384, L: 0=l0w2 1=l1w2 2=pw2   (8 jt x 4 ks)
#define WS_W2LO 49152
#define WS_W3HI 98304    // L*2048,  L: 0=l0w3 1=l1w3 2=pw3   (1 jt x 4 ks, cols padded to 16)
#define WS_W3LO 104448
#define WS_W1HI 110592   // L*4096,  L: 0=l0w1 1=l1w1 2=pw1   (8 jt x 1 ks, K padded to 32)
#define WS_W1LO 122880

__device__ __forceinline__ float elu_f(float x) {
    return x > 0.0f ? x : (__expf(x) - 1.0f);
}
__device__ __forceinline__ ushort f2bf_u(float x) {
    __bf16 h = (__bf16)x;
    return __builtin_bit_cast(ushort, h);
}
__device__ __forceinline__ float bfu2f(ushort u) {
    return (float)__builtin_bit_cast(__bf16, u);
}
// split v into hi/lo bf16
__device__ __forceinline__ void split2(float v, __bf16& h, __bf16& l) {
    h = (__bf16)v;
    l = (__bf16)(v - (float)h);
}
__device__ __forceinline__ void split_store_scalar(float v, ushort* hi, ushort* lo, int off) {
    __bf16 h, l; split2(v, h, l);
    hi[off] = __builtin_bit_cast(ushort, h);
    lo[off] = __builtin_bit_cast(ushort, l);
}

// ---- weight prep: fp32 -> bf16 hi/lo fragments ----
__global__ void prep_kernel(const float* __restrict__ w20, const float* __restrict__ w21,
                            const float* __restrict__ w22,
                            const float* __restrict__ w30, const float* __restrict__ w31,
                            const float* __restrict__ w32,
                            const float* __restrict__ w10, const float* __restrict__ w11,
                            const float* __restrict__ w12,
                            ushort* __restrict__ ws)
{
    const int gid = blockIdx.x * 256 + threadIdx.x;
    if (gid < 3 * 16384) {                       // W2: 128x128
        const int layer = gid >> 14, idx = gid & 16383;
        const float* w = layer == 0 ? w20 : layer == 1 ? w21 : w22;
        const int k = idx >> 7, j = idx & 127;
        const float x = w[idx];
        const int ks = k >> 5, kk = k & 31, jt = j >> 4, jj = j & 15;
        const int lane = ((kk >> 3) << 4) | jj, i = kk & 7;
        const int off = (((jt * 4 + ks) * 64 + lane) << 3) + i;
        __bf16 h, l; split2(x, h, l);
        ws[WS_W2HI + layer * 16384 + off] = __builtin_bit_cast(ushort, h);
        ws[WS_W2LO + layer * 16384 + off] = __builtin_bit_cast(ushort, l);
    } else if (gid < 3 * 16384 + 3 * 2048) {     // W3: 128x8 padded to 16 cols
        const int g2 = gid - 3 * 16384;
        const int layer = g2 >> 11, idx = g2 & 2047;
        const float* w = layer == 0 ? w30 : layer == 1 ? w31 : w32;
        const int i = idx & 7, lane = (idx >> 3) & 63, ks = idx >> 9;
        const int k = ks * 32 + (lane >> 4) * 8 + i, j = lane & 15;
        const float x = (j < OO) ? w[k * OO + j] : 0.0f;
        __bf16 h, l; split2(x, h, l);
        ws[WS_W3HI + layer * 2048 + idx] = __builtin_bit_cast(ushort, h);
        ws[WS_W3LO + layer * 2048 + idx] = __builtin_bit_cast(ushort, l);
    } else {                                     // W1: Kx128, K padded to 32
        const int g1 = gid - (3 * 16384 + 3 * 2048);
        const int layer = g1 >> 12, idx = g1 & 4095;
        const float* w = layer == 0 ? w10 : layer == 1 ? w11 : w12;
        const int i = idx & 7, lane = (idx >> 3) & 63, jt = idx >> 9;
        const int k = (lane >> 4) * 8 + i, j = jt * 16 + (lane & 15);
        const int Kr = (layer == 2) ? 16 : 8;
        const float x = (k < Kr) ? w[k * HH + j] : 0.0f;
        __bf16 h, l; split2(x, h, l);
        ws[WS_W1HI + layer * 4096 + idx] = __builtin_bit_cast(ushort, h);
        ws[WS_W1LO + layer * 4096 + idx] = __builtin_bit_cast(ushort, l);
    }
}

// epilogue: acc (4 consecutive output features) + bias -> elu -> split -> 2x ds_write_b64
__device__ __forceinline__ void epi_store(f32x4 a, const float* __restrict__ bias, int jb,
                                          ushort* __restrict__ dH, ushort* __restrict__ dL,
                                          int off)
{
    const float4 bb = *(const float4*)(bias + jb);
    bf16x4 vh, vl;
    {
        float v0 = elu_f(a[0] + bb.x), v1 = elu_f(a[1] + bb.y);
        float v2 = elu_f(a[2] + bb.z), v3 = elu_f(a[3] + bb.w);
        __bf16 h, l;
        split2(v0, h, l); vh[0] = h; vl[0] = l;
        split2(v1, h, l); vh[1] = h; vl[1] = l;
        split2(v2, h, l); vh[2] = h; vl[2] = l;
        split2(v3, h, l); vh[3] = h; vl[3] = l;
    }
    *(bf16x4*)(dH + off) = vh;
    *(bf16x4*)(dL + off) = vl;
}

__global__ __launch_bounds__(512, 4) void mlps_kernel(
    const int*   __restrict__ adj,
    const float* __restrict__ fop,
    const float* __restrict__ fmab,
    const float* __restrict__ l0b1, const float* __restrict__ l0b2, const float* __restrict__ l0b3,
    const float* __restrict__ l1b1, const float* __restrict__ l1b2, const float* __restrict__ l1b3,
    const float* __restrict__ pb1,  const float* __restrict__ pb2,  const float* __restrict__ pb3,
    const ushort* __restrict__ wsf,
    float* __restrict__ out)
{
    __shared__ __align__(16) ushort hbuf[2][2][TM * ASTRB];   // [br][hi/lo]
    __shared__ __align__(16) ushort gbuf[2][2][TM * ASTRB];
    __shared__ float fmS[N_MAC * FF];
    __shared__ __align__(16) ushort xinH[TM * FF], xinL[TM * FF];
    __shared__ __align__(16) ushort xopH[TM * FF], xopL[TM * FF];
    __shared__ __align__(16) ushort catH[TM * 16], catL[TM * 16];

    const int tid  = threadIdx.x;
    const int wv   = tid >> 6;
    const int lane = tid & 63;
    const int lrow = lane & 15;       // activation row within 16-row tile (D col)
    const int lk   = lane >> 4;       // k-octet / D row quad
    const int row0 = blockIdx.x * TM;
    const int b    = row0 / N_OPC;

    // ---- stage: machine feats (fp32), op feats (split planes)
    fmS[tid] = fmab[b * N_MAC * FF + tid];
    if (tid < TM * FF)
        split_store_scalar(fop[row0 * FF + tid], xopH, xopL, tid);
    __syncthreads();

    // ---- aggregation: xin[r][f] = sum_m adj[r][m] * fm[m][f]
    if (tid < TM * FF) {
        const int r = tid >> 3, f = tid & 7;
        const int* arow = adj + (row0 + r) * N_MAC;
        float a = 0.0f;
        #pragma unroll
        for (int m4 = 0; m4 < N_MAC; m4 += 4) {
            const int4 av = *(const int4*)(arow + m4);
            a = fmaf((float)av.x, fmS[(m4 + 0) * FF + f], a);
            a = fmaf((float)av.y, fmS[(m4 + 1) * FF + f], a);
            a = fmaf((float)av.z, fmS[(m4 + 2) * FF + f], a);
            a = fmaf((float)av.w, fmS[(m4 + 3) * FF + f], a);
        }
        split_store_scalar(a, xinH, xinL, tid);
    }
    __syncthreads();

    // ---- input layers (K=8 pad 32): waves 0-3 br0, 4-7 br1; 2 jtiles, 2 rowtiles each
    {
        const int br = wv >> 2, jt0 = (wv & 3) * 2;
        const ushort* xH = br ? xopH : xinH;
        const ushort* xL = br ? xopL : xinL;
        const bf16x8* WH = (const bf16x8*)(wsf + WS_W1HI + br * 4096);
        const bf16x8* WL = (const bf16x8*)(wsf + WS_W1LO + br * 4096);
        const float* b1 = br ? l1b1 : l0b1;
        bf16x8 XH[2] = {}, XL[2] = {};
        if (lk == 0) {
            #pragma unroll
            for (int rt = 0; rt < 2; ++rt) {
                XH[rt] = *(const bf16x8*)(xH + (rt * 16 + lrow) * 8);
                XL[rt] = *(const bf16x8*)(xL + (rt * 16 + lrow) * 8);
            }
        }
        f32x4 acc[2][2] = {};
        #pragma unroll
        for (int jtl = 0; jtl < 2; ++jtl) {
            const bf16x8 wh = WH[(jt0 + jtl) * 64 + lane];
            const bf16x8 wl = WL[(jt0 + jtl) * 64 + lane];
            #pragma unroll
            for (int rt = 0; rt < 2; ++rt) {
                acc[jtl][rt] = __builtin_amdgcn_mfma_f32_16x16x32_bf16(wh, XH[rt], acc[jtl][rt], 0, 0, 0);
                acc[jtl][rt] = __builtin_amdgcn_mfma_f32_16x16x32_bf16(wl, XH[rt], acc[jtl][rt], 0, 0, 0);
                acc[jtl][rt] = __builtin_amdgcn_mfma_f32_16x16x32_bf16(wh, XL[rt], acc[jtl][rt], 0, 0, 0);
            }
        }
        ushort* dH = hbuf[br][0];
        ushort* dL = hbuf[br][1];
        #pragma unroll
        for (int jtl = 0; jtl < 2; ++jtl) {
            const int jb = (jt0 + jtl) * 16 + lk * 4;
            #pragma unroll
            for (int rt = 0; rt < 2; ++rt)
                epi_store(acc[jtl][rt], b1, jb, dH, dL, (rt * 16 + lrow) * ASTRB + jb);
        }
    }
    __syncthreads();

    // ---- heavy layers (128x128): waves 0-3 br0, 4-7 br1; 2 jtiles x 2 rowtiles
    {
        const int br = wv >> 2, jt0 = (wv & 3) * 2;
        const ushort* aH = hbuf[br][0];
        const ushort* aL = hbuf[br][1];
        const bf16x8* WH = (const bf16x8*)(wsf + WS_W2HI + br * 16384);
        const bf16x8* WL = (const bf16x8*)(wsf + WS_W2LO + br * 16384);
        f32x4 acc[2][2] = {};
        #pragma unroll
        for (int ks = 0; ks < 4; ++ks) {
            bf16x8 xh[2], xl[2];
            #pragma unroll
            for (int rt = 0; rt < 2; ++rt) {
                const int ab = (rt * 16 + lrow) * ASTRB + ks * 32 + lk * 8;
                xh[rt] = *(const bf16x8*)(aH + ab);
                xl[rt] = *(const bf16x8*)(aL + ab);
            }
            #pragma unroll
            for (int jtl = 0; jtl < 2; ++jtl) {
                const bf16x8 wh = WH[((jt0 + jtl) * 4 + ks) * 64 + lane];
                const bf16x8 wl = WL[((jt0 + jtl) * 4 + ks) * 64 + lane];
                #pragma unroll
                for (int rt = 0; rt < 2; ++rt) {
                    acc[jtl][rt] = __builtin_amdgcn_mfma_f32_16x16x32_bf16(wh, xh[rt], acc[jtl][rt], 0, 0, 0);
                    acc[jtl][rt] = __builtin_amdgcn_mfma_f32_16x16x32_bf16(wl, xh[rt], acc[jtl][rt], 0, 0, 0);
                    acc[jtl][rt] = __builtin_amdgcn_mfma_f32_16x16x32_bf16(wh, xl[rt], acc[jtl][rt], 0, 0, 0);
                }
            }
        }
        const float* b2 = br ? l1b2 : l0b2;
        ushort* dH = gbuf[br][0];
        ushort* dL = gbuf[br][1];
        #pragma unroll
        for (int jtl = 0; jtl < 2; ++jtl) {
            const int jb = (jt0 + jtl) * 16 + lk * 4;
            #pragma unroll
            for (int rt = 0; rt < 2; ++rt)
                epi_store(acc[jtl][rt], b2, jb, dH, dL, (rt * 16 + lrow) * ASTRB + jb);
        }
    }
    __syncthreads();

    // ---- branch output layers (128 -> 8 pad 16): waves 0-3
    if (wv < 4) {
        const int br = wv >> 1, rt = wv & 1;
        const ushort* aH = gbuf[br][0];
        const ushort* aL = gbuf[br][1];
        const bf16x8* WH = (const bf16x8*)(wsf + WS_W3HI + br * 2048);
        const bf16x8* WL = (const bf16x8*)(wsf + WS_W3LO + br * 2048);
        f32x4 acc = {};
        #pragma unroll
        for (int ks = 0; ks < 4; ++ks) {
            const int ab = (rt * 16 + lrow) * ASTRB + ks * 32 + lk * 8;
            const bf16x8 xh = *(const bf16x8*)(aH + ab);
            const bf16x8 xl = *(const bf16x8*)(aL + ab);
            const bf16x8 wh = WH[ks * 64 + lane];
            const bf16x8 wl = WL[ks * 64 + lane];
            acc = __builtin_amdgcn_mfma_f32_16x16x32_bf16(wh, xh, acc, 0, 0, 0);
            acc = __builtin_amdgcn_mfma_f32_16x16x32_bf16(wl, xh, acc, 0, 0, 0);
            acc = __builtin_amdgcn_mfma_f32_16x16x32_bf16(wh, xl, acc, 0, 0, 0);
        }
        if (lk < 2) {   // valid output features j = lk*4 .. lk*4+3 (0..7)
            const float* b3 = br ? l1b3 : l0b3;
            epi_store(acc, b3, lk * 4, catH, catL,
                      (rt * 16 + lrow) * 16 + br * OO + lk * 4);
        }
    }
    __syncthreads();

    // ---- proj input layer (K=16 pad 32): wave wv -> jtile wv, 2 rowtiles
    {
        const bf16x8* WH = (const bf16x8*)(wsf + WS_W1HI + 2 * 4096);
        const bf16x8* WL = (const bf16x8*)(wsf + WS_W1LO + 2 * 4096);
        bf16x8 XH[2] = {}, XL[2] = {};
        if (lk < 2) {
            #pragma unroll
            for (int rt = 0; rt < 2; ++rt) {
                XH[rt] = *(const bf16x8*)(catH + (rt * 16 + lrow) * 16 + lk * 8);
                XL[rt] = *(const bf16x8*)(catL + (rt * 16 + lrow) * 16 + lk * 8);
            }
        }
        f32x4 acc[2] = {};
        const bf16x8 wh = WH[wv * 64 + lane];
        const bf16x8 wl = WL[wv * 64 + lane];
        #pragma unroll
        for (int rt = 0; rt < 2; ++rt) {
            acc[rt] = __builtin_amdgcn_mfma_f32_16x16x32_bf16(wh, XH[rt], acc[rt], 0, 0, 0);
            acc[rt] = __builtin_amdgcn_mfma_f32_16x16x32_bf16(wl, XH[rt], acc[rt], 0, 0, 0);
            acc[rt] = __builtin_amdgcn_mfma_f32_16x16x32_bf16(wh, XL[rt], acc[rt], 0, 0, 0);
        }
        const int jb = wv * 16 + lk * 4;
        #pragma unroll
        for (int rt = 0; rt < 2; ++rt)
            epi_store(acc[rt], pb1, jb, hbuf[0][0], hbuf[0][1],
                      (rt * 16 + lrow) * ASTRB + jb);
    }
    __syncthreads();

    // ---- proj heavy layer (128x128): wave wv -> jtile wv, 2 rowtiles
    {
        const ushort* aH = hbuf[0][0];
        const ushort* aL = hbuf[0][1];
        const bf16x8* WH = (const bf16x8*)(wsf + WS_W2HI + 2 * 16384);
        const bf16x8* WL = (const bf16x8*)(wsf + WS_W2LO + 2 * 16384);
        f32x4 acc[2] = {};
        #pragma unroll
        for (int ks = 0; ks < 4; ++ks) {
            const bf16x8 wh = WH[(wv * 4 + ks) * 64 + lane];
            const bf16x8 wl = WL[(wv * 4 + ks) * 64 + lane];
            #pragma unroll
            for (int rt = 0; rt < 2; ++rt) {
                const int ab = (rt * 16 + lrow) * ASTRB + ks * 32 + lk * 8;
                const bf16x8 xh = *(const bf16x8*)(aH + ab);
                const bf16x8 xl = *(const bf16x8*)(aL + ab);
                acc[rt] = __builtin_amdgcn_mfma_f32_16x16x32_bf16(wh, xh, acc[rt], 0, 0, 0);
                acc[rt] = __builtin_amdgcn_mfma_f32_16x16x32_bf16(wl, xh, acc[rt], 0, 0, 0);
                acc[rt] = __builtin_amdgcn_mfma_f32_16x16x32_bf16(wh, xl, acc[rt], 0, 0, 0);
            }
        }
        const int jb = wv * 16 + lk * 4;
        #pragma unroll
        for (int rt = 0; rt < 2; ++rt)
            epi_store(acc[rt], pb2, jb, gbuf[0][0], gbuf[0][1],
                      (rt * 16 + lrow) * ASTRB + jb);
    }
    __syncthreads();

    // ---- proj output layer (128 -> 8): waves 0,1 -> rowtiles, dwordx4 store
    if (wv < 2) {
        const int rt = wv;
        const ushort* aH = gbuf[0][0];
        const ushort* aL = gbuf[0][1];
        const bf16x8* WH = (const bf16x8*)(wsf + WS_W3HI + 2 * 2048);
        const bf16x8* WL = (const bf16x8*)(wsf + WS_W3LO + 2 * 2048);
        f32x4 acc = {};
        #pragma unroll
        for (int ks = 0; ks < 4; ++ks) {
            const int ab = (rt * 16 + lrow) * ASTRB + ks * 32 + lk * 8;
            const bf16x8 xh = *(const bf16x8*)(aH + ab);
            const bf16x8 xl = *(const bf16x8*)(aL + ab);
            const bf16x8 wh = WH[ks * 64 + lane];
            const bf16x8 wl = WL[ks * 64 + lane];
            acc = __builtin_amdgcn_mfma_f32_16x16x32_bf16(wh, xh, acc, 0, 0, 0);
            acc = __builtin_amdgcn_mfma_f32_16x16x32_bf16(wl, xh, acc, 0, 0, 0);
            acc = __builtin_amdgcn_mfma_f32_16x16x32_bf16(wh, xl, acc, 0, 0, 0);
        }
        if (lk < 2) {
            const float4 bb = *(const float4*)(pb3 + lk * 4);
            float4 o;
            o.x = acc[0] + bb.x; o.y = acc[1] + bb.y;
            o.z = acc[2] + bb.z; o.w = acc[3] + bb.w;
            *(float4*)(out + (row0 + rt * 16 + lrow) * OO + lk * 4) = o;
        }
    }
}

extern "C" void kernel_launch(void* const* d_in, const int* in_sizes, int n_in,
                              void* d_out, int out_size, void* d_ws, size_t ws_size,
                              hipStream_t stream) {
    (void)in_sizes; (void)n_in; (void)out_size; (void)ws_size;
    const int*   adj  = (const int*)  d_in[0];
    const float* fop  = (const float*)d_in[1];
    const float* fmab = (const float*)d_in[2];
    const float* l0w1 = (const float*)d_in[3];
    const float* l0b1 = (const float*)d_in[4];
    const float* l0w2 = (const float*)d_in[5];
    const float* l0b2 = (const float*)d_in[6];
    const float* l0w3 = (const float*)d_in[7];
    const float* l0b3 = (const float*)d_in[8];
    const float* l1w1 = (const float*)d_in[9];
    const float* l1b1 = (const float*)d_in[10];
    const float* l1w2 = (const float*)d_in[11];
    const float* l1b2 = (const float*)d_in[12];
    const float* l1w3 = (const float*)d_in[13];
    const float* l1b3 = (const float*)d_in[14];
    const float* pw1  = (const float*)d_in[15];
    const float* pb1  = (const float*)d_in[16];
    const float* pw2  = (const float*)d_in[17];
    const float* pb2  = (const float*)d_in[18];
    const float* pw3  = (const float*)d_in[19];
    const float* pb3  = (const float*)d_in[20];
    float* out = (float*)d_out;
    ushort* wsf = (ushort*)d_ws;

    prep_kernel<<<dim3(264), dim3(256), 0, stream>>>(
        l0w2, l1w2, pw2, l0w3, l1w3, pw3, l0w1, l1w1, pw1, wsf);

    const int grid = (BB * N_OPC) / TM;   // 512
    mlps_kernel<<<dim3(grid), dim3(512), 0, stream>>>(
        adj, fop, fmab,
        l0b1, l0b2, l0b3,
        l1b1, l1b2, l1b3,
        pb1, pb2, pb3,
        wsf, out);
}